// Round 2
// baseline (406.293 us; speedup 1.0000x reference)
//
#include <hip/hip_runtime.h>

#define KK 50000
#define EE 128
#define HH 512
#define DIN 513

typedef short bh8 __attribute__((ext_vector_type(8)));
typedef float fx16 __attribute__((ext_vector_type(16)));

__device__ __forceinline__ short f2b(float f) {
  unsigned u = __float_as_uint(f);
  u = u + 0x7fffu + ((u >> 16) & 1u);
  return (short)(u >> 16);
}
__device__ __forceinline__ float b2f(short b) {
  return __uint_as_float(((unsigned)(unsigned short)b) << 16);
}
__device__ __forceinline__ float sigm(float x) { return 1.f / (1.f + __expf(-x)); }
__device__ __forceinline__ float tanh_(float x) {
  float ax = fabsf(x);
  float e = __expf(-2.f * ax);
  float t = (1.f - e) / (1.f + e);
  return copysignf(t, x);
}

// alpha[r] = dot(km[r,:], o_e) ; 16 lanes per row, 8 f32 each
__global__ void k_alpha(const float* __restrict__ km, const float* __restrict__ oe,
                        float* __restrict__ alpha) {
  int t = blockIdx.x * 256 + threadIdx.x;
  int r = t >> 4, j = t & 15;
  if (r >= KK) return;
  const float4* p = (const float4*)(km + (size_t)r * EE + j * 8);
  const float4* q = (const float4*)(oe + j * 8);
  float4 a0 = p[0], a1 = p[1], b0 = q[0], b1 = q[1];
  float s = a0.x * b0.x + a0.y * b0.y + a0.z * b0.z + a0.w * b0.w
          + a1.x * b1.x + a1.y * b1.y + a1.z * b1.z + a1.w * b1.w;
  s += __shfl_xor(s, 1); s += __shfl_xor(s, 2);
  s += __shfl_xor(s, 4); s += __shfl_xor(s, 8);
  if (j == 0) alpha[r] = s;
}

// Pack W_hh f32 [1536][512] -> bf16 B_packed[(g*64+cb)*512 + n][8]
// element j of octet = W_hh[g*512+n][cb*8+j]
__global__ void k_wpack(const float* __restrict__ whh, short* __restrict__ bp) {
  int o = blockIdx.x * 256 + threadIdx.x;  // < 98304
  int n = o & 511;
  int gk = o >> 9;           // g*64+cb, 0..191
  int g = gk >> 6, cb = gk & 63;
  const float* src = whh + ((size_t)(g * 512 + n)) * 512 + cb * 8;
  float4 f0 = *(const float4*)src;
  float4 f1 = *(const float4*)(src + 4);
  bh8 w;
  w[0] = f2b(f0.x); w[1] = f2b(f0.y); w[2] = f2b(f0.z); w[3] = f2b(f0.w);
  w[4] = f2b(f1.x); w[5] = f2b(f1.y); w[6] = f2b(f1.z); w[7] = f2b(f1.w);
  *(bh8*)(bp + (size_t)o * 8) = w;
}

// gix[j] = dot(W_ih[j,:], concat(ex_e, s)) ; one wave per output. Also zero hkp.
__global__ void k_gix(const float* __restrict__ wih, const float* __restrict__ exe,
                      const float* __restrict__ sv, float* __restrict__ gix,
                      float* __restrict__ hkp) {
  int t = threadIdx.x;
  if (blockIdx.x < 2) {
    int g = blockIdx.x * 256 + t;
    hkp[g] = 0.f;
  }
  int w = blockIdx.x * 4 + (t >> 6);
  int lane = t & 63;
  float s1 = sv[0];
  float sum = 0.f;
  for (int d = lane; d < DIN; d += 64) {
    float xv = (d < 512) ? exe[d] : s1;
    sum += wih[(size_t)w * DIN + d] * xv;
  }
  sum += __shfl_xor(sum, 1); sum += __shfl_xor(sum, 2);
  sum += __shfl_xor(sum, 4); sum += __shfl_xor(sum, 8);
  sum += __shfl_xor(sum, 16); sum += __shfl_xor(sum, 32);
  if (lane == 0) gix[w] = sum;
}

// single-block softmax over alpha[50000] -> beta
__global__ void k_softmax(const float* __restrict__ alpha, float* __restrict__ beta) {
  __shared__ float red[16];
  __shared__ float stat[2];
  int t = threadIdx.x;  // 1024
  float m = -1e30f;
  for (int i = t; i < KK; i += 1024) m = fmaxf(m, alpha[i]);
  for (int o = 1; o < 64; o <<= 1) m = fmaxf(m, __shfl_xor(m, o));
  if ((t & 63) == 0) red[t >> 6] = m;
  __syncthreads();
  if (t == 0) {
    float mm = red[0];
    for (int i = 1; i < 16; ++i) mm = fmaxf(mm, red[i]);
    stat[0] = mm;
  }
  __syncthreads();
  float Mx = stat[0];
  float ss = 0.f;
  for (int i = t; i < KK; i += 1024) ss += __expf(alpha[i] - Mx);
  for (int o = 1; o < 64; o <<= 1) ss += __shfl_xor(ss, o);
  if ((t & 63) == 0) red[t >> 6] = ss;
  __syncthreads();
  if (t == 0) {
    float tot = 0.f;
    for (int i = 0; i < 16; ++i) tot += red[i];
    stat[1] = tot;
  }
  __syncthreads();
  float inv = 1.f / stat[1];
  for (int i = t; i < KK; i += 1024) beta[i] = __expf(alpha[i] - Mx) * inv;
}

// Fused: h->bf16 LDS staging (+hkp partials), gh = h @ W_hh^T via MFMA, GRU gates, h_new
// BM=64 rows/block, 8 waves (2m x 4n), wave tile 32x32x(3 gates), mfma_f32_32x32x16_bf16
// A LDS layout: [cb 0..63][row 0..63][8], slab stride 520 shorts (pad 8)
// 2 blocks/CU (LDS ~69 KB), 4 waves/SIMD; B prefetched 3-deep from L2 (4 buffers)
__global__ __launch_bounds__(512, 4) void k_gemm(
    const float* __restrict__ h, const float* __restrict__ beta,
    const float* __restrict__ gix, const float* __restrict__ b_ih,
    const float* __restrict__ b_hh, const short* __restrict__ bp,
    float* __restrict__ hkp, float* __restrict__ out) {
  __shared__ short Abuf[64 * 520];
  __shared__ float hk[512];
  __shared__ float Lbeta[64];
  const int t = threadIdx.x;
  const int r0 = blockIdx.x * 64;
  hk[t] = 0.f;

  const int kb = t & 63;   // column-octet (c>>3)
  const int wid = t >> 6;  // wave id 0..7
  float hp[8] = {0.f, 0.f, 0.f, 0.f, 0.f, 0.f, 0.f, 0.f};
  #pragma unroll 2
  for (int pass = 0; pass < 8; ++pass) {
    const int r = pass * 8 + wid;
    const int gr = r0 + r;
    float v[8];
    float bv = 0.f;
    if (gr < KK) {
      const float4* p = (const float4*)(h + (size_t)gr * HH + kb * 8);
      float4 x0 = p[0], x1 = p[1];
      v[0] = x0.x; v[1] = x0.y; v[2] = x0.z; v[3] = x0.w;
      v[4] = x1.x; v[5] = x1.y; v[6] = x1.z; v[7] = x1.w;
      bv = beta[gr];
    } else {
      #pragma unroll
      for (int j = 0; j < 8; ++j) v[j] = 0.f;
    }
    if (kb == 0) Lbeta[r] = bv;
    bh8 w;
    #pragma unroll
    for (int j = 0; j < 8; ++j) { hp[j] += bv * v[j]; w[j] = f2b(v[j]); }
    *(bh8*)&Abuf[kb * 520 + r * 8] = w;
  }
  __syncthreads();
  #pragma unroll
  for (int j = 0; j < 8; ++j) atomicAdd(&hk[kb * 8 + j], hp[j]);
  __syncthreads();
  atomicAdd(&hkp[t], hk[t]);

  const int lane = t & 63;
  const int l31 = lane & 31;
  const int lh = lane >> 5;
  const int wm = wid >> 2;  // 0..1
  const int wn = wid & 3;   // 0..3
  const short* Ab = &Abuf[lh * 520 + (wm * 32 + l31) * 8];
  float* out1 = out + 1;

  for (int ni = 0; ni < 4; ++ni) {
    const int col = ni * 128 + wn * 32 + l31;
    const short* bpc = bp + ((size_t)(lh * 512 + col)) * 8;
    fx16 acc0, acc1, acc2;
    #pragma unroll
    for (int q = 0; q < 16; ++q) { acc0[q] = 0.f; acc1[q] = 0.f; acc2[q] = 0.f; }

    bh8 b0[3], b1[3], b2[3], b3[3];
    auto LDB3 = [&](bh8* d, int sp) {
      d[0] = *(const bh8*)(bpc + (size_t)sp * 8192);
      d[1] = *(const bh8*)(bpc + 262144 + (size_t)sp * 8192);
      d[2] = *(const bh8*)(bpc + 524288 + (size_t)sp * 8192);
    };
    auto STEP = [&](int s, const bh8* cur, bh8* nxt) {
      bh8 a = *(const bh8*)(Ab + s * 1040);
      acc0 = __builtin_amdgcn_mfma_f32_32x32x16_bf16(a, cur[0], acc0, 0, 0, 0);
      acc1 = __builtin_amdgcn_mfma_f32_32x32x16_bf16(a, cur[1], acc1, 0, 0, 0);
      acc2 = __builtin_amdgcn_mfma_f32_32x32x16_bf16(a, cur[2], acc2, 0, 0, 0);
      LDB3(nxt, (s + 3) & 31);  // 3-deep prefetch; wraps harmlessly at tail
    };
    LDB3(b0, 0);
    LDB3(b1, 1);
    LDB3(b2, 2);
    for (int u = 0; u < 32; u += 4) {
      STEP(u + 0, b0, b3);
      STEP(u + 1, b1, b0);
      STEP(u + 2, b2, b1);
      STEP(u + 3, b3, b2);
    }

    // epilogue: gates + h_new
    const int cb = col >> 3, c7 = col & 7;
    const float gxr = gix[col], gxz = gix[col + 512], gxn = gix[col + 1024];
    const float bir = b_ih[col], biz = b_ih[col + 512], bin = b_ih[col + 1024];
    const float bhr = b_hh[col], bhz = b_hh[col + 512], bhn = b_hh[col + 1024];
    const int lrb = wm * 32 + 4 * lh;
    #pragma unroll
    for (int q = 0; q < 16; ++q) {
      const int lr = lrb + (q & 3) + 8 * (q >> 2);
      const int gr = r0 + lr;
      if (gr < KK) {
        const float bv = Lbeta[lr];
        const float rv = sigm(acc0[q] + bv * gxr + bir + bhr);
        const float zv = sigm(acc1[q] + bv * gxz + biz + bhz);
        const float nv = tanh_(bv * gxn + bin + rv * (acc2[q] + bhn));
        const float ho = b2f(Abuf[cb * 520 + lr * 8 + c7]);
        out1[(size_t)gr * HH + col] = (1.f - zv) * nv + zv * ho;
      }
    }
  }
}

// predict_score = score_W[0:512].ex_e + score_W[512:1024].hkp + score_b
__global__ void k_score(const float* __restrict__ sw, const float* __restrict__ sb,
                        const float* __restrict__ exe, const float* __restrict__ hkp,
                        float* __restrict__ out) {
  __shared__ float red[8];
  int t = threadIdx.x;  // 512
  float v = sw[t] * exe[t] + sw[512 + t] * hkp[t];
  for (int o = 1; o < 64; o <<= 1) v += __shfl_xor(v, o);
  if ((t & 63) == 0) red[t >> 6] = v;
  __syncthreads();
  if (t == 0) {
    float s = sb[0];
    for (int i = 0; i < 8; ++i) s += red[i];
    out[0] = s;
  }
}

extern "C" void kernel_launch(void* const* d_in, const int* in_sizes, int n_in,
                              void* d_out, int out_size, void* d_ws, size_t ws_size,
                              hipStream_t stream) {
  const float* o_e  = (const float*)d_in[0];
  const float* ex_e = (const float*)d_in[1];
  const float* s    = (const float*)d_in[2];
  const float* h    = (const float*)d_in[3];
  const float* km   = (const float*)d_in[4];
  const float* W_ih = (const float*)d_in[5];
  const float* W_hh = (const float*)d_in[6];
  const float* b_ih = (const float*)d_in[7];
  const float* b_hh = (const float*)d_in[8];
  const float* sW   = (const float*)d_in[9];
  const float* sb   = (const float*)d_in[10];
  float* out = (float*)d_out;

  float* wsf   = (float*)d_ws;
  float* alpha = wsf;            // 50000
  float* beta  = wsf + 50048;    // 50000
  float* gix   = wsf + 100096;   // 1536
  float* hkp   = wsf + 101632;   // 512
  short* bp    = (short*)(wsf + 102400);  // 1,572,864 B

  k_alpha<<<3125, 256, 0, stream>>>(km, o_e, alpha);
  k_wpack<<<384, 256, 0, stream>>>(W_hh, bp);
  k_gix<<<384, 256, 0, stream>>>(W_ih, ex_e, s, gix, hkp);
  k_softmax<<<1, 1024, 0, stream>>>(alpha, beta);
  k_gemm<<<782, 512, 0, stream>>>(h, beta, gix, b_ih, b_hh, bp, hkp, out);
  k_score<<<1, 512, 0, stream>>>(sW, sb, ex_e, hkp, out);
}

// Round 3
// 310.532 us; speedup vs baseline: 1.3084x; 1.3084x over previous
//
#include <hip/hip_runtime.h>

#define KK 50000
#define EE 128
#define HH 512
#define DIN 513

typedef short bh8 __attribute__((ext_vector_type(8)));
typedef float fx16 __attribute__((ext_vector_type(16)));

__device__ __forceinline__ short f2b(float f) {
  unsigned u = __float_as_uint(f);
  u = u + 0x7fffu + ((u >> 16) & 1u);
  return (short)(u >> 16);
}
__device__ __forceinline__ float b2f(short b) {
  return __uint_as_float(((unsigned)(unsigned short)b) << 16);
}
__device__ __forceinline__ float sigm(float x) { return 1.f / (1.f + __expf(-x)); }
__device__ __forceinline__ float tanh_(float x) {
  float ax = fabsf(x);
  float e = __expf(-2.f * ax);
  float t = (1.f - e) / (1.f + e);
  return copysignf(t, x);
}

// alpha[r] = dot(km[r,:], o_e) ; 16 lanes per row, 8 f32 each
__global__ void k_alpha(const float* __restrict__ km, const float* __restrict__ oe,
                        float* __restrict__ alpha) {
  int t = blockIdx.x * 256 + threadIdx.x;
  int r = t >> 4, j = t & 15;
  if (r >= KK) return;
  const float4* p = (const float4*)(km + (size_t)r * EE + j * 8);
  const float4* q = (const float4*)(oe + j * 8);
  float4 a0 = p[0], a1 = p[1], b0 = q[0], b1 = q[1];
  float s = a0.x * b0.x + a0.y * b0.y + a0.z * b0.z + a0.w * b0.w
          + a1.x * b1.x + a1.y * b1.y + a1.z * b1.z + a1.w * b1.w;
  s += __shfl_xor(s, 1); s += __shfl_xor(s, 2);
  s += __shfl_xor(s, 4); s += __shfl_xor(s, 8);
  if (j == 0) alpha[r] = s;
}

// Pack W_hh f32 [1536][512] -> bf16 B_packed[(g*64+cb)*512 + n][8]
// element j of octet = W_hh[g*512+n][cb*8+j]
__global__ void k_wpack(const float* __restrict__ whh, short* __restrict__ bp) {
  int o = blockIdx.x * 256 + threadIdx.x;  // < 98304
  int n = o & 511;
  int gk = o >> 9;           // g*64+cb, 0..191
  int g = gk >> 6, cb = gk & 63;
  const float* src = whh + ((size_t)(g * 512 + n)) * 512 + cb * 8;
  float4 f0 = *(const float4*)src;
  float4 f1 = *(const float4*)(src + 4);
  bh8 w;
  w[0] = f2b(f0.x); w[1] = f2b(f0.y); w[2] = f2b(f0.z); w[3] = f2b(f0.w);
  w[4] = f2b(f1.x); w[5] = f2b(f1.y); w[6] = f2b(f1.z); w[7] = f2b(f1.w);
  *(bh8*)(bp + (size_t)o * 8) = w;
}

// gix[j] = dot(W_ih[j,:], concat(ex_e, s)) ; one wave per output. Also zero hkp.
__global__ void k_gix(const float* __restrict__ wih, const float* __restrict__ exe,
                      const float* __restrict__ sv, float* __restrict__ gix,
                      float* __restrict__ hkp) {
  int t = threadIdx.x;
  if (blockIdx.x < 2) {
    int g = blockIdx.x * 256 + t;
    hkp[g] = 0.f;
  }
  int w = blockIdx.x * 4 + (t >> 6);
  int lane = t & 63;
  float s1 = sv[0];
  float sum = 0.f;
  for (int d = lane; d < DIN; d += 64) {
    float xv = (d < 512) ? exe[d] : s1;
    sum += wih[(size_t)w * DIN + d] * xv;
  }
  sum += __shfl_xor(sum, 1); sum += __shfl_xor(sum, 2);
  sum += __shfl_xor(sum, 4); sum += __shfl_xor(sum, 8);
  sum += __shfl_xor(sum, 16); sum += __shfl_xor(sum, 32);
  if (lane == 0) gix[w] = sum;
}

// single-block softmax over alpha[50000] -> beta
__global__ void k_softmax(const float* __restrict__ alpha, float* __restrict__ beta) {
  __shared__ float red[16];
  __shared__ float stat[2];
  int t = threadIdx.x;  // 1024
  float m = -1e30f;
  for (int i = t; i < KK; i += 1024) m = fmaxf(m, alpha[i]);
  for (int o = 1; o < 64; o <<= 1) m = fmaxf(m, __shfl_xor(m, o));
  if ((t & 63) == 0) red[t >> 6] = m;
  __syncthreads();
  if (t == 0) {
    float mm = red[0];
    for (int i = 1; i < 16; ++i) mm = fmaxf(mm, red[i]);
    stat[0] = mm;
  }
  __syncthreads();
  float Mx = stat[0];
  float ss = 0.f;
  for (int i = t; i < KK; i += 1024) ss += __expf(alpha[i] - Mx);
  for (int o = 1; o < 64; o <<= 1) ss += __shfl_xor(ss, o);
  if ((t & 63) == 0) red[t >> 6] = ss;
  __syncthreads();
  if (t == 0) {
    float tot = 0.f;
    for (int i = 0; i < 16; ++i) tot += red[i];
    stat[1] = tot;
  }
  __syncthreads();
  float inv = 1.f / stat[1];
  for (int i = t; i < KK; i += 1024) beta[i] = __expf(alpha[i] - Mx) * inv;
}

// Fused GEMM+GRU. BM=128 rows/block, 512 thr (8 waves, 2wm x 4wn), wave tile
// 64r x 32c x 3 gates, mfma_f32_32x32x16_bf16.
// A panel (h->bf16) full-K in LDS: [cb 0..63][row 0..127][8], stride 1040 shorts.
// B staged from packed global (bp) through LDS via global_load_lds, double-buffered
// chunks of [3 gates][K=16][128 cols] = 12 KB. One barrier+vmcnt(0) per chunk.
__global__ __launch_bounds__(512, 2) void k_gemm(
    const float* __restrict__ h, const float* __restrict__ beta,
    const float* __restrict__ gix, const float* __restrict__ b_ih,
    const float* __restrict__ b_hh, const short* __restrict__ bp,
    float* __restrict__ hkp, float* __restrict__ out) {
  __shared__ short Abuf[64 * 1040];   // 133,120 B
  __shared__ short Bbuf[2][6144];     //  24,576 B
  __shared__ float Lbeta[128];        //     512 B
  float* hk = (float*)&Bbuf[0][0];    // 2 KB overlay, used only pre-loop

  const int t = threadIdx.x;
  const int r0 = blockIdx.x * 128;
  hk[t] = 0.f;

  // ---- Stage A (h -> bf16 LDS) + beta-weighted partials for hkp ----
  const int kb = t & 63;   // K-octet
  const int wid = t >> 6;  // wave id 0..7
  float hp[8] = {0.f, 0.f, 0.f, 0.f, 0.f, 0.f, 0.f, 0.f};
  #pragma unroll 2
  for (int pass = 0; pass < 16; ++pass) {
    const int r = pass * 8 + wid;
    const int gr = r0 + r;
    float v[8];
    float bv = 0.f;
    if (gr < KK) {
      const float4* p = (const float4*)(h + (size_t)gr * HH + kb * 8);
      float4 x0 = p[0], x1 = p[1];
      v[0] = x0.x; v[1] = x0.y; v[2] = x0.z; v[3] = x0.w;
      v[4] = x1.x; v[5] = x1.y; v[6] = x1.z; v[7] = x1.w;
      bv = beta[gr];
    } else {
      #pragma unroll
      for (int j = 0; j < 8; ++j) v[j] = 0.f;
    }
    if (kb == 0) Lbeta[r] = bv;
    bh8 w;
    #pragma unroll
    for (int j = 0; j < 8; ++j) { hp[j] += bv * v[j]; w[j] = f2b(v[j]); }
    *(bh8*)&Abuf[kb * 1040 + r * 8] = w;
  }
  __syncthreads();
  #pragma unroll
  for (int j = 0; j < 8; ++j) atomicAdd(&hk[kb * 8 + j], hp[j]);
  __syncthreads();
  atomicAdd(&hkp[t], hk[t]);
  __syncthreads();  // hk reads done before B staging overwrites Bbuf[0]

  // ---- Main loop: 128 chunk-steps (ni 0..3 col-groups x kc 0..31 K-chunks) ----
  const int lane = t & 63;
  const int l31 = lane & 31;
  const int lh = lane >> 5;
  const int wm = wid >> 2;  // 0..1
  const int wn = wid & 3;   // 0..3
  float* out1 = out + 1;

  // stage chunk sn into Bbuf[sn&1]: 768 x 16B slots
  auto STAGE = [&](int sn) {
    const int nin = sn >> 5, kcn = sn & 31, sb = sn & 1;
    {
      const int slot = t;
      const int go = slot >> 7, c = slot & 127;
      const int g = go >> 1, ol = go & 1;
      const short* src = bp + (((size_t)(g * 64 + 2 * kcn + ol)) * 512 + nin * 128 + c) * 8;
      __builtin_amdgcn_global_load_lds(
          (const __attribute__((address_space(1))) void*)src,
          (__attribute__((address_space(3))) void*)&Bbuf[sb][slot * 8], 16, 0, 0);
    }
    if (t < 256) {
      const int slot = 512 + t;
      const int go = slot >> 7, c = slot & 127;
      const int g = go >> 1, ol = go & 1;
      const short* src = bp + (((size_t)(g * 64 + 2 * kcn + ol)) * 512 + nin * 128 + c) * 8;
      __builtin_amdgcn_global_load_lds(
          (const __attribute__((address_space(1))) void*)src,
          (__attribute__((address_space(3))) void*)&Bbuf[sb][slot * 8], 16, 0, 0);
    }
  };

  STAGE(0);
  asm volatile("s_waitcnt vmcnt(0)" ::: "memory");
  __syncthreads();

  fx16 acc00, acc01, acc02, acc10, acc11, acc12;

  for (int s = 0; s < 128; ++s) {
    const int sb = s & 1;
    const int kc = s & 31;
    const int ni = s >> 5;
    if (kc == 0) {
      #pragma unroll
      for (int q = 0; q < 16; ++q) {
        acc00[q] = 0.f; acc01[q] = 0.f; acc02[q] = 0.f;
        acc10[q] = 0.f; acc11[q] = 0.f; acc12[q] = 0.f;
      }
    }
    if (s < 127) STAGE(s + 1);

    const int aoff = (2 * kc + lh) * 1040 + (wm * 64 + l31) * 8;
    bh8 a0 = *(const bh8*)&Abuf[aoff];
    bh8 a1 = *(const bh8*)&Abuf[aoff + 256];
    const int bbase = lh * 1024 + (wn * 32 + l31) * 8;
    bh8 br = *(const bh8*)&Bbuf[sb][bbase];
    bh8 bz = *(const bh8*)&Bbuf[sb][bbase + 2048];
    bh8 bn = *(const bh8*)&Bbuf[sb][bbase + 4096];

    acc00 = __builtin_amdgcn_mfma_f32_32x32x16_bf16(a0, br, acc00, 0, 0, 0);
    acc01 = __builtin_amdgcn_mfma_f32_32x32x16_bf16(a0, bz, acc01, 0, 0, 0);
    acc02 = __builtin_amdgcn_mfma_f32_32x32x16_bf16(a0, bn, acc02, 0, 0, 0);
    acc10 = __builtin_amdgcn_mfma_f32_32x32x16_bf16(a1, br, acc10, 0, 0, 0);
    acc11 = __builtin_amdgcn_mfma_f32_32x32x16_bf16(a1, bz, acc11, 0, 0, 0);
    acc12 = __builtin_amdgcn_mfma_f32_32x32x16_bf16(a1, bn, acc12, 0, 0, 0);

    if (kc == 31) {
      // epilogue for this 128-col group
      const int col = ni * 128 + wn * 32 + l31;
      const int cb = col >> 3, c7 = col & 7;
      const float gxr = gix[col], gxz = gix[col + 512], gxn = gix[col + 1024];
      const float bir = b_ih[col], biz = b_ih[col + 512], bin = b_ih[col + 1024];
      const float bhr = b_hh[col], bhz = b_hh[col + 512], bhn = b_hh[col + 1024];
      #define EPI(A0, A1, A2, MIOFF)                                           \
      {                                                                        \
        const int lrb = wm * 64 + (MIOFF) + 4 * lh;                            \
        _Pragma("unroll")                                                      \
        for (int q = 0; q < 16; ++q) {                                         \
          const int lr = lrb + (q & 3) + 8 * (q >> 2);                         \
          const int gr = r0 + lr;                                              \
          if (gr < KK) {                                                       \
            const float bv = Lbeta[lr];                                        \
            const float rv = sigm(A0[q] + bv * gxr + bir + bhr);               \
            const float zv = sigm(A1[q] + bv * gxz + biz + bhz);               \
            const float nv = tanh_(bv * gxn + bin + rv * (A2[q] + bhn));       \
            const float ho = b2f(Abuf[cb * 1040 + lr * 8 + c7]);               \
            out1[(size_t)gr * HH + col] = (1.f - zv) * nv + zv * ho;           \
          }                                                                    \
        }                                                                      \
      }
      EPI(acc00, acc01, acc02, 0)
      EPI(acc10, acc11, acc12, 32)
      #undef EPI
    }

    asm volatile("s_waitcnt vmcnt(0)" ::: "memory");
    __syncthreads();
  }
}

// predict_score = score_W[0:512].ex_e + score_W[512:1024].hkp + score_b
__global__ void k_score(const float* __restrict__ sw, const float* __restrict__ sb,
                        const float* __restrict__ exe, const float* __restrict__ hkp,
                        float* __restrict__ out) {
  __shared__ float red[8];
  int t = threadIdx.x;  // 512
  float v = sw[t] * exe[t] + sw[512 + t] * hkp[t];
  for (int o = 1; o < 64; o <<= 1) v += __shfl_xor(v, o);
  if ((t & 63) == 0) red[t >> 6] = v;
  __syncthreads();
  if (t == 0) {
    float s = sb[0];
    for (int i = 0; i < 8; ++i) s += red[i];
    out[0] = s;
  }
}

extern "C" void kernel_launch(void* const* d_in, const int* in_sizes, int n_in,
                              void* d_out, int out_size, void* d_ws, size_t ws_size,
                              hipStream_t stream) {
  const float* o_e  = (const float*)d_in[0];
  const float* ex_e = (const float*)d_in[1];
  const float* s    = (const float*)d_in[2];
  const float* h    = (const float*)d_in[3];
  const float* km   = (const float*)d_in[4];
  const float* W_ih = (const float*)d_in[5];
  const float* W_hh = (const float*)d_in[6];
  const float* b_ih = (const float*)d_in[7];
  const float* b_hh = (const float*)d_in[8];
  const float* sW   = (const float*)d_in[9];
  const float* sb   = (const float*)d_in[10];
  float* out = (float*)d_out;

  float* wsf   = (float*)d_ws;
  float* alpha = wsf;            // 50000
  float* beta  = wsf + 50048;    // 50000
  float* gix   = wsf + 100096;   // 1536
  float* hkp   = wsf + 101632;   // 512
  short* bp    = (short*)(wsf + 102400);  // 1,572,864 B

  k_alpha<<<3125, 256, 0, stream>>>(km, o_e, alpha);
  k_wpack<<<384, 256, 0, stream>>>(W_hh, bp);
  k_gix<<<384, 256, 0, stream>>>(W_ih, ex_e, s, gix, hkp);
  k_softmax<<<1, 1024, 0, stream>>>(alpha, beta);
  k_gemm<<<391, 512, 0, stream>>>(h, beta, gix, b_ih, b_hh, bp, hkp, out);
  k_score<<<1, 512, 0, stream>>>(sW, sb, ex_e, hkp, out);
}